// Round 1
// baseline (32.956 us; speedup 1.0000x reference)
//
#include <hip/hip_runtime.h>

#define Bq 32
#define Sq 8
#define Lq 128
#define Dq 768
#define Aq 10
#define Tq 8

constexpr int D4 = Dq / 4;  // 192 float4 columns

// ---------------- mean pool: stage 1 (partial sums over 32-row chunks) ----
__global__ __launch_bounds__(192) void pool_partial_k(
    const float* __restrict__ emb, const float* __restrict__ mask,
    float* __restrict__ ws)
{
    int bs  = blockIdx.x;   // 0..B*S-1
    int ch  = blockIdx.y;   // 0..3 (chunk of 32 rows)
    int tid = threadIdx.x;  // 0..191

    const float4* eb = (const float4*)(emb + ((size_t)bs * Lq + ch * 32) * Dq);
    const float*  mb = mask + (size_t)bs * Lq + ch * 32;

    float4 acc = make_float4(0.f, 0.f, 0.f, 0.f);
#pragma unroll 4
    for (int l = 0; l < 32; ++l) {
        float  mv = mb[l];                       // uniform -> scalar load
        float4 v  = eb[(size_t)l * D4 + tid];    // coalesced 16B/lane
        acc.x += v.x * mv; acc.y += v.y * mv;
        acc.z += v.z * mv; acc.w += v.w * mv;
    }
    ((float4*)ws)[((size_t)(bs * 4 + ch)) * D4 + tid] = acc;
}

// ---------------- mean pool: stage 2 (reduce partials, divide by count) ---
__global__ __launch_bounds__(192) void pool_final_k(
    const float* __restrict__ ws, const float* __restrict__ mask,
    float* __restrict__ out)
{
    int bs  = blockIdx.x;
    int tid = threadIdx.x;

    __shared__ float red[Lq];
    if (tid < Lq) red[tid] = mask[(size_t)bs * Lq + tid];
    __syncthreads();
    for (int s = 64; s > 0; s >>= 1) {
        if (tid < s) red[tid] += red[tid + s];
        __syncthreads();
    }
    float inv = 1.0f / fmaxf(red[0], 1.0f);   // clip(count, 1, None)

    const float4* w4 = (const float4*)ws;
    size_t base = (size_t)bs * 4 * D4;
    float4 a = w4[base + tid];
    float4 b = w4[base + D4 + tid];
    float4 c = w4[base + 2 * D4 + tid];
    float4 d = w4[base + 3 * D4 + tid];
    float4 r;
    r.x = (a.x + b.x + c.x + d.x) * inv;
    r.y = (a.y + b.y + c.y + d.y) * inv;
    r.z = (a.z + b.z + c.z + d.z) * inv;
    r.w = (a.w + b.w + c.w + d.w) * inv;
    ((float4*)out)[(size_t)bs * D4 + tid] = r;
}

// ---------------- mean pool: fused fallback (no workspace) ----------------
__global__ __launch_bounds__(192) void pool_full_k(
    const float* __restrict__ emb, const float* __restrict__ mask,
    float* __restrict__ out)
{
    int bs  = blockIdx.x;
    int tid = threadIdx.x;

    __shared__ float red[Lq];
    if (tid < Lq) red[tid] = mask[(size_t)bs * Lq + tid];
    __syncthreads();
    for (int s = 64; s > 0; s >>= 1) {
        if (tid < s) red[tid] += red[tid + s];
        __syncthreads();
    }
    float inv = 1.0f / fmaxf(red[0], 1.0f);

    const float4* eb = (const float4*)(emb + (size_t)bs * Lq * Dq);
    const float*  mb = mask + (size_t)bs * Lq;
    float4 acc = make_float4(0.f, 0.f, 0.f, 0.f);
#pragma unroll 4
    for (int l = 0; l < Lq; ++l) {
        float  mv = mb[l];
        float4 v  = eb[(size_t)l * D4 + tid];
        acc.x += v.x * mv; acc.y += v.y * mv;
        acc.z += v.z * mv; acc.w += v.w * mv;
    }
    float4 r = make_float4(acc.x * inv, acc.y * inv, acc.z * inv, acc.w * inv);
    ((float4*)out)[(size_t)bs * D4 + tid] = r;
}

// ---------------- arg embeddings (predicate / arg0 / arg1) ----------------
__global__ __launch_bounds__(192) void arg_embed_k(
    const int* __restrict__ sids, const float* __restrict__ emb,
    const int* __restrict__ pred, const int* __restrict__ a0,
    const int* __restrict__ a1, float* __restrict__ outbase)
{
    int bsa = blockIdx.x;            // 0..B*S*A-1
    int set = blockIdx.y;            // 0:pred 1:arg0 2:arg1
    int bs  = bsa / Aq;
    const int* ids = (set == 0) ? pred : ((set == 1) ? a0 : a1);

    int tid  = threadIdx.x;
    int lane = tid & 63;
    int wv   = tid >> 6;

    __shared__ int sid[Lq];
    __shared__ int wcnt[3][Tq];
    __shared__ unsigned long long wb[3];
    __shared__ int mlist[Lq];

    if (tid < Lq) sid[tid] = sids[(size_t)bs * Lq + tid];

    int idreg[Tq];
#pragma unroll
    for (int t = 0; t < Tq; ++t) idreg[t] = ids[(size_t)bsa * Tq + t];
    __syncthreads();

    int myid = (tid < Lq) ? sid[tid] : -2;

    // per-token match counts via 64-lane ballots (3 waves)
#pragma unroll
    for (int t = 0; t < Tq; ++t) {
        bool m = (idreg[t] != 0) && (myid == idreg[t]);
        unsigned long long b = __ballot(m);
        if (lane == 0) wcnt[wv][t] = __popcll(b);
    }
    __syncthreads();

    // uniform: last t with count>0 (loop overwrite semantics in reference)
    int chosen = -1, ccount = 0;
#pragma unroll
    for (int t = Tq - 1; t >= 0; --t) {
        if (chosen == -1) {
            int c = wcnt[0][t] + wcnt[1][t] + wcnt[2][t];
            if (c > 0) { chosen = idreg[t]; ccount = c; }
        }
    }

    // deterministic matched-row list via ballot prefix popcount
    bool m = (myid == chosen);   // myid>=0 for tid<L, -2 otherwise; chosen==-1 never matches
    unsigned long long b = __ballot(m);
    if (lane == 0) wb[wv] = b;
    __syncthreads();
    int pos = (int)__popcll(b & ((1ull << lane) - 1ull));
    if (wv > 0) pos += (int)__popcll(wb[0]);
    if (wv > 1) pos += (int)__popcll(wb[1]);
    if (m) mlist[pos] = tid;
    __syncthreads();

    // accumulate matched rows (usually 0-2), uniform loop
    const float4* eb = (const float4*)(emb + (size_t)bs * Lq * Dq);
    float4 acc = make_float4(0.f, 0.f, 0.f, 0.f);
    for (int i = 0; i < ccount; ++i) {
        int l = mlist[i];
        float4 v = eb[(size_t)l * D4 + tid];
        acc.x += v.x; acc.y += v.y; acc.z += v.z; acc.w += v.w;
    }
    float inv = (ccount > 0) ? 1.0f / (float)ccount : 0.0f;
    float4 r = make_float4(acc.x * inv, acc.y * inv, acc.z * inv, acc.w * inv);

    float* outp = outbase + ((size_t)set * (Bq * Sq * Aq) + bsa) * Dq;
    ((float4*)outp)[tid] = r;
}

extern "C" void kernel_launch(void* const* d_in, const int* in_sizes, int n_in,
                              void* d_out, int out_size, void* d_ws, size_t ws_size,
                              hipStream_t stream) {
    const int*   sids = (const int*)d_in[0];
    const float* mask = (const float*)d_in[1];
    const float* emb  = (const float*)d_in[2];
    const int*   pred = (const int*)d_in[3];
    const int*   a0   = (const int*)d_in[4];
    const int*   a1   = (const int*)d_in[5];
    float* out = (float*)d_out;

    size_t ws_need = (size_t)Bq * Sq * 4 * Dq * sizeof(float);  // 3 MiB
    if (ws_size >= ws_need) {
        dim3 g1(Bq * Sq, 4);
        pool_partial_k<<<g1, 192, 0, stream>>>(emb, mask, (float*)d_ws);
        pool_final_k<<<Bq * Sq, 192, 0, stream>>>((const float*)d_ws, mask, out);
    } else {
        pool_full_k<<<Bq * Sq, 192, 0, stream>>>(emb, mask, out);
    }

    dim3 g2(Bq * Sq * Aq, 3);
    arg_embed_k<<<g2, 192, 0, stream>>>(sids, emb, pred, a0, a1,
                                        out + (size_t)Bq * Sq * Dq);
}

// Round 2
// 27.657 us; speedup vs baseline: 1.1916x; 1.1916x over previous
//
#include <hip/hip_runtime.h>

#define Bq 32
#define Sq 8
#define Lq 128
#define Dq 768
#define Aq 10
#define Tq 8

constexpr int D4    = Dq / 4;          // 192 float4 columns
constexpr int NPOOL = Bq * Sq * 4;     // 1024 pool blocks (bs x D-quarter)
constexpr int NBSA  = Bq * Sq * Aq;    // 2560
constexpr int NARG  = NBSA * 3;        // 7680 arg blocks

__global__ __launch_bounds__(192) void srl_fused_k(
    const int* __restrict__ sids, const float* __restrict__ mask,
    const float* __restrict__ emb, const int* __restrict__ pred,
    const int* __restrict__ a0, const int* __restrict__ a1,
    float* __restrict__ out)
{
    int bid = blockIdx.x;
    int tid = threadIdx.x;

    if (bid < NPOOL) {
        // ---------------- mean pool: one block = (b,s) x 48-column quarter --
        int bs = bid >> 2;
        int q  = bid & 3;

        __shared__ float  marr[Lq];
        __shared__ float  msum;
        __shared__ float4 red[4][48];

        if (tid < Lq) marr[tid] = mask[(size_t)bs * Lq + tid];

        // mask count: wave 0 only, shuffle reduce (no barrier tree)
        if (tid < 64) {
            float mv = mask[(size_t)bs * Lq + tid] +
                       mask[(size_t)bs * Lq + 64 + tid];
            for (int off = 32; off > 0; off >>= 1)
                mv += __shfl_xor(mv, off);
            if (tid == 0) msum = mv;
        }
        __syncthreads();

        int g = tid / 48;          // row group 0..3 (32 rows each)
        int c = tid - g * 48;      // column within quarter 0..47

        const float4* eb = (const float4*)emb +
                           (size_t)bs * Lq * D4 + q * 48 + c;
        float4 acc = make_float4(0.f, 0.f, 0.f, 0.f);
#pragma unroll 8
        for (int l = 0; l < 32; ++l) {
            float  mv = marr[g * 32 + l];          // LDS broadcast
            float4 v  = eb[(size_t)(g * 32 + l) * D4];
            acc.x += v.x * mv; acc.y += v.y * mv;
            acc.z += v.z * mv; acc.w += v.w * mv;
        }
        red[g][c] = acc;
        __syncthreads();

        if (tid < 48) {
            float4 a = red[0][tid], b = red[1][tid];
            float4 cc = red[2][tid], d = red[3][tid];
            float inv = 1.0f / fmaxf(msum, 1.0f);
            float4 r;
            r.x = (a.x + b.x + cc.x + d.x) * inv;
            r.y = (a.y + b.y + cc.y + d.y) * inv;
            r.z = (a.z + b.z + cc.z + d.z) * inv;
            r.w = (a.w + b.w + cc.w + d.w) * inv;
            ((float4*)out)[(size_t)bs * D4 + q * 48 + tid] = r;
        }
        return;
    }

    // ---------------- arg embeddings (predicate / arg0 / arg1) ------------
    int j   = bid - NPOOL;
    int set = j / NBSA;            // 0:pred 1:arg0 2:arg1
    int bsa = j - set * NBSA;      // 0..2559
    int bs  = bsa / Aq;
    const int* ids = (set == 0) ? pred : ((set == 1) ? a0 : a1);

    int lane = tid & 63;
    int wv   = tid >> 6;

    __shared__ int sid[Lq];
    __shared__ int wcnt[3][Tq];
    __shared__ unsigned long long wb[3];
    __shared__ int mlist[Lq];

    if (tid < Lq) sid[tid] = sids[(size_t)bs * Lq + tid];

    int idreg[Tq];
#pragma unroll
    for (int t = 0; t < Tq; ++t) idreg[t] = ids[(size_t)bsa * Tq + t];
    __syncthreads();

    int myid = (tid < Lq) ? sid[tid] : -2;

    // per-token match counts via 64-lane ballots (3 waves)
#pragma unroll
    for (int t = 0; t < Tq; ++t) {
        bool m = (idreg[t] != 0) && (myid == idreg[t]);
        unsigned long long b = __ballot(m);
        if (lane == 0) wcnt[wv][t] = __popcll(b);
    }
    __syncthreads();

    // uniform: last t with count>0 (loop-overwrite semantics of reference)
    int chosen = -1, ccount = 0;
#pragma unroll
    for (int t = Tq - 1; t >= 0; --t) {
        if (chosen == -1) {
            int cnt = wcnt[0][t] + wcnt[1][t] + wcnt[2][t];
            if (cnt > 0) { chosen = idreg[t]; ccount = cnt; }
        }
    }

    // deterministic matched-row list via ballot prefix popcount
    bool m = (myid == chosen);     // chosen==-1 never matches (ids >= 0)
    unsigned long long b = __ballot(m);
    if (lane == 0) wb[wv] = b;
    __syncthreads();
    int pos = (int)__popcll(b & ((1ull << lane) - 1ull));
    if (wv > 0) pos += (int)__popcll(wb[0]);
    if (wv > 1) pos += (int)__popcll(wb[1]);
    if (m) mlist[pos] = tid;
    __syncthreads();

    // accumulate matched rows (usually 0-2), uniform loop
    const float4* eb = (const float4*)emb + (size_t)bs * Lq * D4;
    float4 acc = make_float4(0.f, 0.f, 0.f, 0.f);
    for (int i = 0; i < ccount; ++i) {
        int l = mlist[i];
        float4 v = eb[(size_t)l * D4 + tid];
        acc.x += v.x; acc.y += v.y; acc.z += v.z; acc.w += v.w;
    }
    float inv = (ccount > 0) ? 1.0f / (float)ccount : 0.0f;
    float4 r = make_float4(acc.x * inv, acc.y * inv, acc.z * inv, acc.w * inv);

    float* outp = out + (size_t)Bq * Sq * Dq +
                  ((size_t)set * NBSA + bsa) * Dq;
    ((float4*)outp)[tid] = r;
}

extern "C" void kernel_launch(void* const* d_in, const int* in_sizes, int n_in,
                              void* d_out, int out_size, void* d_ws, size_t ws_size,
                              hipStream_t stream) {
    const int*   sids = (const int*)d_in[0];
    const float* mask = (const float*)d_in[1];
    const float* emb  = (const float*)d_in[2];
    const int*   pred = (const int*)d_in[3];
    const int*   a0   = (const int*)d_in[4];
    const int*   a1   = (const int*)d_in[5];
    float* out = (float*)d_out;

    srl_fused_k<<<NPOOL + NARG, 192, 0, stream>>>(sids, mask, emb,
                                                  pred, a0, a1, out);
}

// Round 3
// 25.955 us; speedup vs baseline: 1.2697x; 1.0656x over previous
//
#include <hip/hip_runtime.h>

#define Bq 32
#define Sq 8
#define Lq 128
#define Dq 768
#define Aq 10
#define Tq 8

constexpr int D4    = Dq / 4;       // 192 float4 columns
constexpr int NBS   = Bq * Sq;      // 256
constexpr int NBSA  = NBS * Aq;     // 2560
constexpr int NPOOL = NBS;          // 256 pool blocks (one per b,s)
constexpr int NARG  = NBS;          // 256 arg blocks (one per b,s; wave=set)

__global__ __launch_bounds__(192) void srl_fused_k(
    const int* __restrict__ sids, const float* __restrict__ mask,
    const float* __restrict__ emb, const int* __restrict__ pred,
    const int* __restrict__ a0, const int* __restrict__ a1,
    float* __restrict__ out)
{
    int bid = blockIdx.x;
    int tid = threadIdx.x;

    if (bid < NPOOL) {
        // ---- mean pool: block = (b,s); thread = float4 column; 128 rows --
        int bs = bid;
        __shared__ float marr[Lq];
        __shared__ float msum;

        if (tid < Lq) marr[tid] = mask[(size_t)bs * Lq + tid];
        if (tid < 64) {
            float mv = mask[(size_t)bs * Lq + tid] +
                       mask[(size_t)bs * Lq + 64 + tid];
            for (int off = 32; off > 0; off >>= 1)
                mv += __shfl_xor(mv, off);
            if (tid == 0) msum = mv;
        }
        __syncthreads();

        const float4* eb = (const float4*)emb + (size_t)bs * Lq * D4 + tid;
        float4 acc = make_float4(0.f, 0.f, 0.f, 0.f);
#pragma unroll 16
        for (int l = 0; l < Lq; ++l) {
            float  mv = marr[l];                 // LDS broadcast (uniform)
            float4 v  = eb[(size_t)l * D4];      // contiguous 3072B per iter
            acc.x += v.x * mv; acc.y += v.y * mv;
            acc.z += v.z * mv; acc.w += v.w * mv;
        }
        float inv = 1.0f / fmaxf(msum, 1.0f);    // clip(count,1,None)
        float4 r = make_float4(acc.x * inv, acc.y * inv,
                               acc.z * inv, acc.w * inv);
        ((float4*)out)[(size_t)bs * D4 + tid] = r;
        return;
    }

    // ---- arg embeddings: block = (b,s); wave = set; loop a = 0..9 --------
    int bs   = bid - NPOOL;
    int set  = tid >> 6;               // wave index = set (0:pred 1:a0 2:a1)
    int lane = tid & 63;
    const int* ids = (set == 0) ? pred : ((set == 1) ? a0 : a1);

    // whole sentence in 2 regs/lane; no LDS, no barriers
    int s0 = sids[(size_t)bs * Lq + lane];
    int s1 = sids[(size_t)bs * Lq + 64 + lane];

    const float4* eb = (const float4*)emb + (size_t)bs * Lq * D4;

    for (int a = 0; a < Aq; ++a) {
        int bsa = bs * Aq + a;
        int idv = (lane < Tq) ? ids[(size_t)bsa * Tq + lane] : 0;

        // last t (descending) whose nonzero id occurs in the sentence
        unsigned long long B0 = 0, B1 = 0;
        int ccount = 0;
#pragma unroll
        for (int t = Tq - 1; t >= 0; --t) {
            if (ccount == 0) {                       // wave-uniform
                int idt = __shfl(idv, t);
                if (idt != 0) {
                    unsigned long long b0 = __ballot(s0 == idt);
                    unsigned long long b1 = __ballot(s1 == idt);
                    int c = (int)(__popcll(b0) + __popcll(b1));
                    if (c > 0) { B0 = b0; B1 = b1; ccount = c; }
                }
            }
        }

        // gather matched rows (uniform bit loops, ascending l: deterministic)
        float4 acc0 = make_float4(0.f, 0.f, 0.f, 0.f);
        float4 acc1 = acc0, acc2 = acc0;
        unsigned long long b = B0;
        while (b) {
            int l = (int)__builtin_ctzll(b); b &= b - 1;
            float4 v0 = eb[(size_t)l * D4 + lane];
            float4 v1 = eb[(size_t)l * D4 + 64 + lane];
            float4 v2 = eb[(size_t)l * D4 + 128 + lane];
            acc0.x += v0.x; acc0.y += v0.y; acc0.z += v0.z; acc0.w += v0.w;
            acc1.x += v1.x; acc1.y += v1.y; acc1.z += v1.z; acc1.w += v1.w;
            acc2.x += v2.x; acc2.y += v2.y; acc2.z += v2.z; acc2.w += v2.w;
        }
        b = B1;
        while (b) {
            int l = (int)__builtin_ctzll(b) + 64; b &= b - 1;
            float4 v0 = eb[(size_t)l * D4 + lane];
            float4 v1 = eb[(size_t)l * D4 + 64 + lane];
            float4 v2 = eb[(size_t)l * D4 + 128 + lane];
            acc0.x += v0.x; acc0.y += v0.y; acc0.z += v0.z; acc0.w += v0.w;
            acc1.x += v1.x; acc1.y += v1.y; acc1.z += v1.z; acc1.w += v1.w;
            acc2.x += v2.x; acc2.y += v2.y; acc2.z += v2.z; acc2.w += v2.w;
        }

        float inv = (ccount > 0) ? 1.0f / (float)ccount : 0.0f;
        float4* o4 = (float4*)out +
                     ((size_t)NBS + (size_t)set * NBSA + bsa) * D4;
        o4[lane]       = make_float4(acc0.x*inv, acc0.y*inv, acc0.z*inv, acc0.w*inv);
        o4[64 + lane]  = make_float4(acc1.x*inv, acc1.y*inv, acc1.z*inv, acc1.w*inv);
        o4[128 + lane] = make_float4(acc2.x*inv, acc2.y*inv, acc2.z*inv, acc2.w*inv);
    }
}

extern "C" void kernel_launch(void* const* d_in, const int* in_sizes, int n_in,
                              void* d_out, int out_size, void* d_ws, size_t ws_size,
                              hipStream_t stream) {
    const int*   sids = (const int*)d_in[0];
    const float* mask = (const float*)d_in[1];
    const float* emb  = (const float*)d_in[2];
    const int*   pred = (const int*)d_in[3];
    const int*   a0   = (const int*)d_in[4];
    const int*   a1   = (const int*)d_in[5];
    float* out = (float*)d_out;

    srl_fused_k<<<NPOOL + NARG, 192, 0, stream>>>(sids, mask, emb,
                                                  pred, a0, a1, out);
}